// Round 1
// baseline (1967.092 us; speedup 1.0000x reference)
//
#include <hip/hip_runtime.h>

constexpr int Hc = 512, Wc = 512, Bc = 4;
constexpr int HWc = Hc * Wc;          // 262144 = 2^18
constexpr int NP  = Bc * HWc;         // 1048576  (B,H,W)
constexpr int NC  = 2 * NP;           // 2097152  (B,2,H,W)
constexpr int NITER = 15;

__device__ __forceinline__ float ld0(const float* p, int h, int w) {
  return (h >= 0 && h < Hc && w >= 0 && w < Wc) ? p[h * Wc + w] : 0.f;
}

// ---- precompute gx, gy, norm_grad, rho_c from x ----
__global__ void k_precompute(const float* __restrict__ x,
                             float* __restrict__ gx, float* __restrict__ gy,
                             float* __restrict__ ng, float* __restrict__ rc) {
  int idx = blockIdx.x * blockDim.x + threadIdx.x;
  if (idx >= NP) return;
  int w = idx & (Wc - 1);
  int h = (idx >> 9) & (Hc - 1);
  int b = idx >> 18;
  const float* I0 = x + (b * 2 + 0) * HWc;
  const float* I1 = x + (b * 2 + 1) * HWc;
  float a00 = ld0(I1, h - 1, w - 1), a01 = ld0(I1, h - 1, w), a02 = ld0(I1, h - 1, w + 1);
  float a10 = ld0(I1, h,     w - 1),                          a12 = ld0(I1, h,     w + 1);
  float a20 = ld0(I1, h + 1, w - 1), a21 = ld0(I1, h + 1, w), a22 = ld0(I1, h + 1, w + 1);
  float gxv = (a00 - a02) + 2.f * (a10 - a12) + (a20 - a22);
  float gyv = (a00 + 2.f * a01 + a02) - (a20 + 2.f * a21 + a22);
  gx[idx] = gxv; gy[idx] = gyv;
  ng[idx] = gxv * gxv + gyv * gyv;
  rc[idx] = I1[h * Wc + w] - I0[h * Wc + w];
}

// ---- phase 1: thresholding + divergence -> u (in place; only same-pixel u reads) ----
__global__ void k_update_u(float* __restrict__ u,
                           const float* __restrict__ p1, const float* __restrict__ p2,
                           const float* __restrict__ gx, const float* __restrict__ gy,
                           const float* __restrict__ ng, const float* __restrict__ rc,
                           const float* __restrict__ wxp, const float* __restrict__ wyp,
                           const float* __restrict__ lamp, const float* __restrict__ thetap) {
  int idx = blockIdx.x * blockDim.x + threadIdx.x;
  if (idx >= NP) return;
  float lam = lamp[0], theta = thetap[0];
  float wx0 = wxp[0], wx1 = wxp[1], wy0 = wyp[0], wy1 = wyp[1];
  int w = idx & (Wc - 1);
  int h = (idx >> 9) & (Hc - 1);
  int b = idx >> 18;
  int hw = h * Wc + w;
  int i0 = b * 2 * HWc + hw;
  int i1 = i0 + HWc;
  float u0 = u[i0], u1 = u[i1];
  float gxv = gx[idx], gyv = gy[idx], ngv = ng[idx];
  float rho = rc[idx] + gxv * u0 + gyv * u1;
  float th = theta * lam * ngv;
  float ar = fabsf(rho);
  float d0, d1;
  if (ar < th) {            // ng > 0 guaranteed here
    float q = rho / ngv; d0 = q * gxv; d1 = q * gyv;
  } else if (ar > th) {
    float s = (rho > 0.f) ? 1.f : ((rho < 0.f) ? -1.f : 0.f);
    float tl = theta * lam; d0 = tl * gxv * s; d1 = tl * gyv * s;
  } else { d0 = 0.f; d1 = 0.f; }
  const float* P1b = p1 + b * 2 * HWc;
  const float* P2b = p2 + b * 2 * HWc;
  float p1c0 = P1b[hw];
  float p1l0 = (w > 0) ? P1b[hw - 1] : 0.f;
  float p1c1 = P1b[HWc + hw];
  float p1l1 = (w > 0) ? P1b[HWc + hw - 1] : 0.f;
  float p2c0 = P2b[hw];
  float p2u0 = (h > 0) ? P2b[hw - Wc] : 0.f;
  float p2c1 = P2b[HWc + hw];
  float p2u1 = (h > 0) ? P2b[HWc + hw - Wc] : 0.f;
  float div0 = wx0 * p1l0 + wx1 * p1c0 + wy0 * p2u0 + wy1 * p2c0;
  float div1 = wx0 * p1l1 + wx1 * p1c1 + wy0 * p2u1 + wy1 * p2c1;
  u[i0] = (u0 - d0) + theta * div0;
  u[i1] = (u1 - d1) + theta * div1;
}

// ---- phase 2: Sobel of u (both channels) + global |.| sums ----
__global__ void k_gradu(const float* __restrict__ u,
                        float* __restrict__ g1, float* __restrict__ g2,
                        float* __restrict__ s2) {
  int idx = blockIdx.x * blockDim.x + threadIdx.x;
  float l1 = 0.f, l2 = 0.f;
  if (idx < NP) {
    int w = idx & (Wc - 1);
    int h = (idx >> 9) & (Hc - 1);
    int b = idx >> 18;
    int hw = h * Wc + w;
    const float* U0 = u + b * 2 * HWc;
    const float* U1 = U0 + HWc;

    float a00 = ld0(U0, h - 1, w - 1), a01 = ld0(U0, h - 1, w), a02 = ld0(U0, h - 1, w + 1);
    float a10 = ld0(U0, h,     w - 1),                          a12 = ld0(U0, h,     w + 1);
    float a20 = ld0(U0, h + 1, w - 1), a21 = ld0(U0, h + 1, w), a22 = ld0(U0, h + 1, w + 1);
    float gx0 = (a00 - a02) + 2.f * (a10 - a12) + (a20 - a22);
    float gy0 = (a00 + 2.f * a01 + a02) - (a20 + 2.f * a21 + a22);

    float b00 = ld0(U1, h - 1, w - 1), b01 = ld0(U1, h - 1, w), b02 = ld0(U1, h - 1, w + 1);
    float b10 = ld0(U1, h,     w - 1),                          b12 = ld0(U1, h,     w + 1);
    float b20 = ld0(U1, h + 1, w - 1), b21 = ld0(U1, h + 1, w), b22 = ld0(U1, h + 1, w + 1);
    float gx1 = (b00 - b02) + 2.f * (b10 - b12) + (b20 - b22);
    float gy1 = (b00 + 2.f * b01 + b02) - (b20 + 2.f * b21 + b22);

    int o = b * 2 * HWc + hw;
    g1[o] = gx0; g1[o + HWc] = gy0;
    g2[o] = gx1; g2[o + HWc] = gy1;
    l1 = fabsf(gx0) + fabsf(gy0);
    l2 = fabsf(gx1) + fabsf(gy1);
  }
  // wave(64) reduce, then cross-wave via LDS, one atomicAdd per block per scalar
  for (int o = 32; o > 0; o >>= 1) {
    l1 += __shfl_down(l1, o, 64);
    l2 += __shfl_down(l2, o, 64);
  }
  __shared__ float sm1[4], sm2[4];
  int lane = threadIdx.x & 63, wid = threadIdx.x >> 6;
  if (lane == 0) { sm1[wid] = l1; sm2[wid] = l2; }
  __syncthreads();
  if (threadIdx.x == 0) {
    atomicAdd(&s2[0], sm1[0] + sm1[1] + sm1[2] + sm1[3]);
    atomicAdd(&s2[1], sm2[0] + sm2[1] + sm2[2] + sm2[3]);
  }
}

// ---- phase 3: p update with global scalars ----
__global__ void k_update_p(float* __restrict__ p1, float* __restrict__ p2,
                           const float* __restrict__ g1, const float* __restrict__ g2,
                           const float* __restrict__ s2,
                           const float* __restrict__ taup, const float* __restrict__ thetap) {
  int i = blockIdx.x * blockDim.x + threadIdx.x;
  if (i >= NC) return;
  float r = taup[0] / thetap[0];
  float inv1 = 1.f / (1.f + r * s2[0]);
  float inv2 = 1.f / (1.f + r * s2[1]);
  p1[i] = (p1[i] + r * g1[i]) * inv1;
  p2[i] = (p2[i] + r * g2[i]) * inv2;
}

extern "C" void kernel_launch(void* const* d_in, const int* in_sizes, int n_in,
                              void* d_out, int out_size, void* d_ws, size_t ws_size,
                              hipStream_t stream) {
  const float* x     = (const float*)d_in[0];
  const float* wx    = (const float*)d_in[1];
  const float* wy    = (const float*)d_in[2];
  const float* lam   = (const float*)d_in[3];
  const float* tau   = (const float*)d_in[4];
  const float* theta = (const float*)d_in[5];
  float* u  = (float*)d_out;          // u lives in d_out
  float* ws = (float*)d_ws;
  float* gx = ws;                     // NP
  float* gy = gx + NP;                // NP
  float* ng = gy + NP;                // NP
  float* rc = ng + NP;                // NP
  float* p1 = rc + NP;                // NC
  float* p2 = p1 + NC;                // NC
  float* g1 = p2 + NC;                // NC
  float* g2 = g1 + NC;                // NC
  float* s  = g2 + NC;                // 2*NITER floats

  hipMemsetAsync(u,  0, (size_t)NC * sizeof(float), stream);
  hipMemsetAsync(p1, 0, (size_t)2 * NC * sizeof(float), stream);   // p1 and p2 contiguous
  hipMemsetAsync(s,  0, (size_t)2 * NITER * sizeof(float), stream);

  dim3 blk(256);
  k_precompute<<<NP / 256, blk, 0, stream>>>(x, gx, gy, ng, rc);
  for (int t = 0; t < NITER; ++t) {
    k_update_u<<<NP / 256, blk, 0, stream>>>(u, p1, p2, gx, gy, ng, rc, wx, wy, lam, theta);
    k_gradu  <<<NP / 256, blk, 0, stream>>>(u, g1, g2, s + 2 * t);
    k_update_p<<<NC / 256, blk, 0, stream>>>(p1, p2, g1, g2, s + 2 * t, tau, theta);
  }
}

// Round 2
// 498.986 us; speedup vs baseline: 3.9422x; 3.9422x over previous
//
#include <hip/hip_runtime.h>

constexpr int Hc = 512, Wc = 512, Bc = 4;
constexpr int HWc = Hc * Wc;          // 262144 = 2^18
constexpr int NP  = Bc * HWc;         // 1048576  (B,H,W)
constexpr int NC  = 2 * NP;           // 2097152  (B,2,H,W)
constexpr int NITER = 15;
constexpr int NBLK = NP / 256;        // 4096 blocks for pixel-grid kernels

__device__ __forceinline__ float ld0(const float* p, int h, int w) {
  return (h >= 0 && h < Hc && w >= 0 && w < Wc) ? p[h * Wc + w] : 0.f;
}

__device__ __forceinline__ void sobel(const float* __restrict__ U, int h, int w,
                                      float& gxo, float& gyo) {
  float a00 = ld0(U, h - 1, w - 1), a01 = ld0(U, h - 1, w), a02 = ld0(U, h - 1, w + 1);
  float a10 = ld0(U, h,     w - 1),                         a12 = ld0(U, h,     w + 1);
  float a20 = ld0(U, h + 1, w - 1), a21 = ld0(U, h + 1, w), a22 = ld0(U, h + 1, w + 1);
  gxo = (a00 - a02) + 2.f * (a10 - a12) + (a20 - a22);
  gyo = (a00 + 2.f * a01 + a02) - (a20 + 2.f * a21 + a22);
}

// ---- precompute gx, gy, norm_grad, rho_c from x ----
__global__ void k_precompute(const float* __restrict__ x,
                             float* __restrict__ gx, float* __restrict__ gy,
                             float* __restrict__ ng, float* __restrict__ rc) {
  int idx = blockIdx.x * blockDim.x + threadIdx.x;
  if (idx >= NP) return;
  int w = idx & (Wc - 1);
  int h = (idx >> 9) & (Hc - 1);
  int b = idx >> 18;
  const float* I0 = x + (b * 2 + 0) * HWc;
  const float* I1 = x + (b * 2 + 1) * HWc;
  float gxv, gyv;
  sobel(I1, h, w, gxv, gyv);
  gx[idx] = gxv; gy[idx] = gyv;
  ng[idx] = gxv * gxv + gyv * gyv;
  rc[idx] = I1[h * Wc + w] - I0[h * Wc + w];
}

// ---- phase 1: thresholding + divergence -> u (in place; only same-pixel u reads) ----
__global__ void k_update_u(float* __restrict__ u,
                           const float* __restrict__ p1, const float* __restrict__ p2,
                           const float* __restrict__ gx, const float* __restrict__ gy,
                           const float* __restrict__ ng, const float* __restrict__ rc,
                           const float* __restrict__ wxp, const float* __restrict__ wyp,
                           const float* __restrict__ lamp, const float* __restrict__ thetap) {
  int idx = blockIdx.x * blockDim.x + threadIdx.x;
  if (idx >= NP) return;
  float lam = lamp[0], theta = thetap[0];
  float wx0 = wxp[0], wx1 = wxp[1], wy0 = wyp[0], wy1 = wyp[1];
  int w = idx & (Wc - 1);
  int h = (idx >> 9) & (Hc - 1);
  int b = idx >> 18;
  int hw = h * Wc + w;
  int i0 = b * 2 * HWc + hw;
  int i1 = i0 + HWc;
  float u0 = u[i0], u1 = u[i1];
  float gxv = gx[idx], gyv = gy[idx], ngv = ng[idx];
  float rho = rc[idx] + gxv * u0 + gyv * u1;
  float th = theta * lam * ngv;
  float ar = fabsf(rho);
  float d0, d1;
  if (ar < th) {            // ng > 0 guaranteed here
    float q = rho / ngv; d0 = q * gxv; d1 = q * gyv;
  } else if (ar > th) {
    float s = (rho > 0.f) ? 1.f : ((rho < 0.f) ? -1.f : 0.f);
    float tl = theta * lam; d0 = tl * gxv * s; d1 = tl * gyv * s;
  } else { d0 = 0.f; d1 = 0.f; }
  const float* P1b = p1 + b * 2 * HWc;
  const float* P2b = p2 + b * 2 * HWc;
  float p1c0 = P1b[hw];
  float p1l0 = (w > 0) ? P1b[hw - 1] : 0.f;
  float p1c1 = P1b[HWc + hw];
  float p1l1 = (w > 0) ? P1b[HWc + hw - 1] : 0.f;
  float p2c0 = P2b[hw];
  float p2u0 = (h > 0) ? P2b[hw - Wc] : 0.f;
  float p2c1 = P2b[HWc + hw];
  float p2u1 = (h > 0) ? P2b[HWc + hw - Wc] : 0.f;
  float div0 = wx0 * p1l0 + wx1 * p1c0 + wy0 * p2u0 + wy1 * p2c0;
  float div1 = wx0 * p1l1 + wx1 * p1c1 + wy0 * p2u1 + wy1 * p2c1;
  u[i0] = (u0 - d0) + theta * div0;
  u[i1] = (u1 - d1) + theta * div1;
}

// ---- phase 2: Sobel of u (both channels), per-block partial |.| sums (NO atomics) ----
__global__ void k_gradu_sum(const float* __restrict__ u, float2* __restrict__ part) {
  int idx = blockIdx.x * blockDim.x + threadIdx.x;
  float l1 = 0.f, l2 = 0.f;
  if (idx < NP) {
    int w = idx & (Wc - 1);
    int h = (idx >> 9) & (Hc - 1);
    int b = idx >> 18;
    const float* U0 = u + b * 2 * HWc;
    const float* U1 = U0 + HWc;
    float gx0, gy0, gx1, gy1;
    sobel(U0, h, w, gx0, gy0);
    sobel(U1, h, w, gx1, gy1);
    l1 = fabsf(gx0) + fabsf(gy0);
    l2 = fabsf(gx1) + fabsf(gy1);
  }
  for (int o = 32; o > 0; o >>= 1) {
    l1 += __shfl_down(l1, o, 64);
    l2 += __shfl_down(l2, o, 64);
  }
  __shared__ float sm1[4], sm2[4];
  int lane = threadIdx.x & 63, wid = threadIdx.x >> 6;
  if (lane == 0) { sm1[wid] = l1; sm2[wid] = l2; }
  __syncthreads();
  if (threadIdx.x == 0) {
    part[blockIdx.x] = make_float2(sm1[0] + sm1[1] + sm1[2] + sm1[3],
                                   sm2[0] + sm2[1] + sm2[2] + sm2[3]);
  }
}

// ---- phase 2b: fold 4096 per-block partials into the two scalars ----
__global__ void k_reduce(const float2* __restrict__ part, float* __restrict__ s2) {
  float l1 = 0.f, l2 = 0.f;
  for (int i = threadIdx.x; i < NBLK; i += 1024) {
    float2 v = part[i];
    l1 += v.x; l2 += v.y;
  }
  for (int o = 32; o > 0; o >>= 1) {
    l1 += __shfl_down(l1, o, 64);
    l2 += __shfl_down(l2, o, 64);
  }
  __shared__ float sm1[16], sm2[16];
  int lane = threadIdx.x & 63, wid = threadIdx.x >> 6;
  if (lane == 0) { sm1[wid] = l1; sm2[wid] = l2; }
  __syncthreads();
  if (threadIdx.x == 0) {
    float a = 0.f, b = 0.f;
    #pragma unroll
    for (int i = 0; i < 16; ++i) { a += sm1[i]; b += sm2[i]; }
    s2[0] = a; s2[1] = b;
  }
}

// ---- phase 3: recompute gradu from u and update p in place ----
__global__ void k_update_p(float* __restrict__ p1, float* __restrict__ p2,
                           const float* __restrict__ u,
                           const float* __restrict__ s2,
                           const float* __restrict__ taup, const float* __restrict__ thetap) {
  int idx = blockIdx.x * blockDim.x + threadIdx.x;
  if (idx >= NP) return;
  float r = taup[0] / thetap[0];
  float inv1 = 1.f / (1.f + r * s2[0]);
  float inv2 = 1.f / (1.f + r * s2[1]);
  int w = idx & (Wc - 1);
  int h = (idx >> 9) & (Hc - 1);
  int b = idx >> 18;
  int hw = h * Wc + w;
  const float* U0 = u + b * 2 * HWc;
  const float* U1 = U0 + HWc;
  float gx0, gy0, gx1, gy1;
  sobel(U0, h, w, gx0, gy0);
  sobel(U1, h, w, gx1, gy1);
  int o = b * 2 * HWc + hw;
  p1[o]       = (p1[o]       + r * gx0) * inv1;
  p1[o + HWc] = (p1[o + HWc] + r * gy0) * inv1;
  p2[o]       = (p2[o]       + r * gx1) * inv2;
  p2[o + HWc] = (p2[o + HWc] + r * gy1) * inv2;
}

extern "C" void kernel_launch(void* const* d_in, const int* in_sizes, int n_in,
                              void* d_out, int out_size, void* d_ws, size_t ws_size,
                              hipStream_t stream) {
  const float* x     = (const float*)d_in[0];
  const float* wx    = (const float*)d_in[1];
  const float* wy    = (const float*)d_in[2];
  const float* lam   = (const float*)d_in[3];
  const float* tau   = (const float*)d_in[4];
  const float* theta = (const float*)d_in[5];
  float* u  = (float*)d_out;          // u lives in d_out
  float* ws = (float*)d_ws;
  float* gx = ws;                     // NP
  float* gy = gx + NP;                // NP
  float* ng = gy + NP;                // NP
  float* rc = ng + NP;                // NP
  float* p1 = rc + NP;                // NC
  float* p2 = p1 + NC;                // NC
  float2* part = (float2*)(p2 + NC);  // NBLK float2
  float* s  = (float*)(part + NBLK);  // 2*NITER floats

  hipMemsetAsync(u,  0, (size_t)NC * sizeof(float), stream);
  hipMemsetAsync(p1, 0, (size_t)2 * NC * sizeof(float), stream);   // p1 and p2 contiguous

  dim3 blk(256);
  k_precompute<<<NBLK, blk, 0, stream>>>(x, gx, gy, ng, rc);
  for (int t = 0; t < NITER; ++t) {
    k_update_u <<<NBLK, blk, 0, stream>>>(u, p1, p2, gx, gy, ng, rc, wx, wy, lam, theta);
    k_gradu_sum<<<NBLK, blk, 0, stream>>>(u, part);
    k_reduce   <<<1, 1024, 0, stream>>>(part, s + 2 * t);
    k_update_p <<<NBLK, blk, 0, stream>>>(p1, p2, u, s + 2 * t, tau, theta);
  }
}

// Round 3
// 475.407 us; speedup vs baseline: 4.1377x; 1.0496x over previous
//
#include <hip/hip_runtime.h>

constexpr int Hc = 512, Wc = 512, Bc = 4;
constexpr int HWc = Hc * Wc;          // 262144
constexpr int NP  = Bc * HWc;         // 1048576
constexpr int NC  = 2 * NP;           // 2097152
constexpr int NITER = 15;
constexpr int TB = 32;                // tile edge
constexpr int HT = TB + 2;            // 34 (1-halo)
constexpr int NT = HT * HT;           // 1156
constexpr int NBLK = NP / (TB * TB);  // 1024 blocks

__device__ __forceinline__ float ld0(const float* p, int h, int w) {
  return (h >= 0 && h < Hc && w >= 0 && w < Wc) ? p[h * Wc + w] : 0.f;
}

// ---- precompute gxy (packed), rho_c from x ----
__global__ void k_pre(const float* __restrict__ x,
                      float2* __restrict__ gxy, float* __restrict__ rc) {
  int idx = blockIdx.x * blockDim.x + threadIdx.x;
  if (idx >= NP) return;
  int w = idx & (Wc - 1);
  int h = (idx >> 9) & (Hc - 1);
  int b = idx >> 18;
  const float* I0 = x + (b * 2 + 0) * HWc;
  const float* I1 = x + (b * 2 + 1) * HWc;
  float a00 = ld0(I1, h - 1, w - 1), a01 = ld0(I1, h - 1, w), a02 = ld0(I1, h - 1, w + 1);
  float a10 = ld0(I1, h,     w - 1),                          a12 = ld0(I1, h,     w + 1);
  float a20 = ld0(I1, h + 1, w - 1), a21 = ld0(I1, h + 1, w), a22 = ld0(I1, h + 1, w + 1);
  float gxv = (a00 - a02) + 2.f * (a10 - a12) + (a20 - a22);
  float gyv = (a00 + 2.f * a01 + a02) - (a20 + 2.f * a21 + a22);
  gxy[idx] = make_float2(gxv, gyv);
  rc[idx]  = I1[h * Wc + w] - I0[h * Wc + w];
}

// ---- fused: u-update (halo-recomputed into LDS, double-buffered) + Sobel |.| partials ----
__global__ void __launch_bounds__(1024)
k_AB(const float* __restrict__ uR, float* __restrict__ uW,
     const float* __restrict__ p1, const float* __restrict__ p2,
     const float2* __restrict__ gxy, const float* __restrict__ rc,
     const float* __restrict__ wxp, const float* __restrict__ wyp,
     const float* __restrict__ lamp, const float* __restrict__ thetap,
     float2* __restrict__ part) {
  __shared__ float su0[HT][HT + 1], su1[HT][HT + 1];
  int blk = blockIdx.x;
  int b = blk >> 8, t = blk & 255;
  int h0 = (t >> 4) << 5, w0 = (t & 15) << 5;
  float lam = lamp[0], theta = thetap[0];
  float wx0 = wxp[0], wx1 = wxp[1], wy0 = wyp[0], wy1 = wyp[1];
  const float* U0 = uR + b * 2 * HWc;
  const float* U1 = U0 + HWc;
  const float* P1 = p1 + b * 2 * HWc;
  const float* P2 = p2 + b * 2 * HWc;
  const float2* G = gxy + b * HWc;
  const float* RC = rc + b * HWc;

  for (int i = threadIdx.x; i < NT; i += 1024) {
    int th = i / HT, tw = i - th * HT;
    int gh = h0 - 1 + th, gw = w0 - 1 + tw;
    float v0 = 0.f, v1 = 0.f;
    if (gh >= 0 && gh < Hc && gw >= 0 && gw < Wc) {
      int hw = gh * Wc + gw;
      float u0 = U0[hw], u1 = U1[hw];
      float2 g = G[hw];
      float ngv = g.x * g.x + g.y * g.y;
      float rho = RC[hw] + g.x * u0 + g.y * u1;
      float th_ = theta * lam * ngv;
      float ar = fabsf(rho);
      float d0, d1;
      if (ar < th_) {                 // ngv > 0 guaranteed
        float q = rho / ngv; d0 = q * g.x; d1 = q * g.y;
      } else if (ar > th_) {
        float s = (rho > 0.f) ? 1.f : ((rho < 0.f) ? -1.f : 0.f);
        float tl = theta * lam; d0 = tl * g.x * s; d1 = tl * g.y * s;
      } else { d0 = 0.f; d1 = 0.f; }
      float p1c0 = P1[hw],             p1c1 = P1[HWc + hw];
      float p1l0 = (gw > 0) ? P1[hw - 1] : 0.f;
      float p1l1 = (gw > 0) ? P1[HWc + hw - 1] : 0.f;
      float p2c0 = P2[hw],             p2c1 = P2[HWc + hw];
      float p2u0 = (gh > 0) ? P2[hw - Wc] : 0.f;
      float p2u1 = (gh > 0) ? P2[HWc + hw - Wc] : 0.f;
      float div0 = wx0 * p1l0 + wx1 * p1c0 + wy0 * p2u0 + wy1 * p2c0;
      float div1 = wx0 * p1l1 + wx1 * p1c1 + wy0 * p2u1 + wy1 * p2c1;
      v0 = (u0 - d0) + theta * div0;
      v1 = (u1 - d1) + theta * div1;
    }
    su0[th][tw] = v0;
    su1[th][tw] = v1;
  }
  __syncthreads();

  int r = threadIdx.x >> 5, c = threadIdx.x & 31;
  float a00 = su0[r][c],     a01 = su0[r][c + 1],     a02 = su0[r][c + 2];
  float a10 = su0[r + 1][c],                          a12 = su0[r + 1][c + 2];
  float a20 = su0[r + 2][c], a21 = su0[r + 2][c + 1], a22 = su0[r + 2][c + 2];
  float gx0 = (a00 - a02) + 2.f * (a10 - a12) + (a20 - a22);
  float gy0 = (a00 + 2.f * a01 + a02) - (a20 + 2.f * a21 + a22);
  float b00 = su1[r][c],     b01 = su1[r][c + 1],     b02 = su1[r][c + 2];
  float b10 = su1[r + 1][c],                          b12 = su1[r + 1][c + 2];
  float b20 = su1[r + 2][c], b21 = su1[r + 2][c + 1], b22 = su1[r + 2][c + 2];
  float gx1 = (b00 - b02) + 2.f * (b10 - b12) + (b20 - b22);
  float gy1 = (b00 + 2.f * b01 + b02) - (b20 + 2.f * b21 + b22);

  float* W0 = uW + b * 2 * HWc;
  int hw = (h0 + r) * Wc + (w0 + c);
  W0[hw]       = su0[r + 1][c + 1];
  W0[HWc + hw] = su1[r + 1][c + 1];

  float l1 = fabsf(gx0) + fabsf(gy0);
  float l2 = fabsf(gx1) + fabsf(gy1);
  for (int o = 32; o > 0; o >>= 1) {
    l1 += __shfl_down(l1, o, 64);
    l2 += __shfl_down(l2, o, 64);
  }
  __shared__ float sm1[16], sm2[16];
  int lane = threadIdx.x & 63, wid = threadIdx.x >> 6;
  if (lane == 0) { sm1[wid] = l1; sm2[wid] = l2; }
  __syncthreads();
  if (threadIdx.x == 0) {
    float a = 0.f, bb = 0.f;
    #pragma unroll
    for (int i = 0; i < 16; ++i) { a += sm1[i]; bb += sm2[i]; }
    part[blockIdx.x] = make_float2(a, bb);
  }
}

// ---- fused: inline reduce of 1024 partials + p-update (Sobel recompute from u) ----
__global__ void __launch_bounds__(1024)
k_Cp(float* __restrict__ p1, float* __restrict__ p2,
     const float* __restrict__ u, const float2* __restrict__ part,
     const float* __restrict__ taup, const float* __restrict__ thetap) {
  __shared__ float red1[16], red2[16];
  float2 pv = part[threadIdx.x];
  float l1 = pv.x, l2 = pv.y;
  for (int o = 32; o > 0; o >>= 1) {
    l1 += __shfl_down(l1, o, 64);
    l2 += __shfl_down(l2, o, 64);
  }
  int lane = threadIdx.x & 63, wid = threadIdx.x >> 6;
  if (lane == 0) { red1[wid] = l1; red2[wid] = l2; }
  __syncthreads();
  if (threadIdx.x == 0) {
    float a = 0.f, bb = 0.f;
    #pragma unroll
    for (int i = 0; i < 16; ++i) { a += red1[i]; bb += red2[i]; }
    red1[0] = a; red2[0] = bb;
  }
  __syncthreads();
  float S1 = red1[0], S2 = red2[0];
  float r_ = taup[0] / thetap[0];
  float inv1 = 1.f / (1.f + r_ * S1);
  float inv2 = 1.f / (1.f + r_ * S2);

  int idx = blockIdx.x * 1024 + threadIdx.x;
  int w = idx & (Wc - 1);
  int h = (idx >> 9) & (Hc - 1);
  int b = idx >> 18;
  int hw = h * Wc + w;
  const float* U0 = u + b * 2 * HWc;
  const float* U1 = U0 + HWc;
  float a00 = ld0(U0, h - 1, w - 1), a01 = ld0(U0, h - 1, w), a02 = ld0(U0, h - 1, w + 1);
  float a10 = ld0(U0, h,     w - 1),                          a12 = ld0(U0, h,     w + 1);
  float a20 = ld0(U0, h + 1, w - 1), a21 = ld0(U0, h + 1, w), a22 = ld0(U0, h + 1, w + 1);
  float gx0 = (a00 - a02) + 2.f * (a10 - a12) + (a20 - a22);
  float gy0 = (a00 + 2.f * a01 + a02) - (a20 + 2.f * a21 + a22);
  float b00 = ld0(U1, h - 1, w - 1), b01 = ld0(U1, h - 1, w), b02 = ld0(U1, h - 1, w + 1);
  float b10 = ld0(U1, h,     w - 1),                          b12 = ld0(U1, h,     w + 1);
  float b20 = ld0(U1, h + 1, w - 1), b21 = ld0(U1, h + 1, w), b22 = ld0(U1, h + 1, w + 1);
  float gx1 = (b00 - b02) + 2.f * (b10 - b12) + (b20 - b22);
  float gy1 = (b00 + 2.f * b01 + b02) - (b20 + 2.f * b21 + b22);

  int o = b * 2 * HWc + hw;
  p1[o]       = (p1[o]       + r_ * gx0) * inv1;
  p1[o + HWc] = (p1[o + HWc] + r_ * gy0) * inv1;
  p2[o]       = (p2[o]       + r_ * gx1) * inv2;
  p2[o + HWc] = (p2[o + HWc] + r_ * gy1) * inv2;
}

extern "C" void kernel_launch(void* const* d_in, const int* in_sizes, int n_in,
                              void* d_out, int out_size, void* d_ws, size_t ws_size,
                              hipStream_t stream) {
  const float* x     = (const float*)d_in[0];
  const float* wx    = (const float*)d_in[1];
  const float* wy    = (const float*)d_in[2];
  const float* lam   = (const float*)d_in[3];
  const float* tau   = (const float*)d_in[4];
  const float* theta = (const float*)d_in[5];
  float* uOut = (float*)d_out;                 // buffer B1
  float* ws = (float*)d_ws;
  float2* gxy = (float2*)ws;                   // NP float2 (8MB)
  float* rc   = (float*)(gxy + NP);            // NP (4MB)
  float* uAlt = rc + NP;                       // NC (8MB)  buffer B0
  float* p1   = uAlt + NC;                     // NC (8MB)
  float* p2   = p1 + NC;                       // NC (8MB)
  float2* part = (float2*)(p2 + NC);           // NBLK float2

  // zero uAlt, p1, p2 (contiguous) in one memset
  hipMemsetAsync(uAlt, 0, (size_t)3 * NC * sizeof(float), stream);

  k_pre<<<NP / 1024, 1024, 0, stream>>>(x, gxy, rc);
  for (int t = 1; t <= NITER; ++t) {
    const float* uR = (t & 1) ? uAlt : uOut;
    float*       uW = (t & 1) ? uOut : uAlt;
    k_AB<<<NBLK, 1024, 0, stream>>>(uR, uW, p1, p2, gxy, rc, wx, wy, lam, theta, part);
    if (t < NITER)
      k_Cp<<<NBLK, 1024, 0, stream>>>(p1, p2, uW, part, tau, theta);
  }
}